// Round 8
// baseline (478.326 us; speedup 1.0000x reference)
//
#include <hip/hip_runtime.h>
#include <hip/hip_cooperative_groups.h>

namespace cg = cooperative_groups;

#define DIM    256
#define HALF   128
#define F0     10
#define F1     25
#define B0     1024
#define M1     10240
#define UNITS  704        // 11264 aggregate rows / 16
#define GRID   704

typedef __attribute__((ext_vector_type(8))) short bf16x8;  // 8 bf16 = 4 VGPRs
typedef __attribute__((ext_vector_type(4))) float f32x4;

#define LSTRIDE 264   // LDS row stride in bf16 elems (528 B, 16B multiple)

__device__ __forceinline__ unsigned short f2bf(float x) {
    union { float f; unsigned u; } v; v.f = x;
    unsigned r = v.u + 0x7fffu + ((v.u >> 16) & 1u);   // RNE
    return (unsigned short)(r >> 16);
}
__device__ __forceinline__ float bf2f(unsigned b) {    // low 16 bits
    union { unsigned u; float f; } v; v.u = b << 16;
    return v.f;
}
__device__ __forceinline__ unsigned packbf(float a, float b) {
    return (unsigned)f2bf(a) | ((unsigned)f2bf(b) << 16);
}

// Gather+mean for 4 rows per wave into LDS bf16 (R4-proven pattern).
template<int NF>
__device__ __forceinline__ void gather4(
    const float* __restrict__ feat,
    const int*   __restrict__ selfIdx,
    const int*   __restrict__ neighIdx,
    int rowbase, int wv, int lane,
    unsigned short (*sh)[16][LSTRIDE])
{
    const float sc = 1.0f / (float)NF;
    #pragma unroll
    for (int rr = 0; rr < 4; ++rr) {
        const int r  = wv * 4 + rr;
        const int si = selfIdx[rowbase + r];                     // wave-uniform scalar
        const float4 sv = *(const float4*)(feat + (size_t)si * DIM + lane * 4);
        *(uint2*)(&sh[0][r][lane * 4]) = make_uint2(packbf(sv.x, sv.y), packbf(sv.z, sv.w));

        float4 a = make_float4(0.f, 0.f, 0.f, 0.f);
        #pragma unroll
        for (int j = 0; j < NF; ++j) {
            const int gi = neighIdx[(rowbase + r) * NF + j];     // wave-uniform scalar
            const float4 v = *(const float4*)(feat + (size_t)gi * DIM + lane * 4);
            a.x += v.x; a.y += v.y; a.z += v.z; a.w += v.w;
        }
        *(uint2*)(&sh[1][r][lane * 4]) =
            make_uint2(packbf(a.x * sc, a.y * sc), packbf(a.z * sc, a.w * sc));
    }
}

// One cooperative kernel: prep -> layer0 (both hops) -> final.
__global__ __launch_bounds__(256, 3) void sage_coop(
    const float* __restrict__ feat,
    const int*   __restrict__ sn0,
    const int*   __restrict__ sn1,
    const int*   __restrict__ sn2,
    const float* __restrict__ W0s,
    const float* __restrict__ W0n,
    const float* __restrict__ W1s,
    const float* __restrict__ W1n,
    unsigned short* __restrict__ bfrag,   // ws: 128 KB
    unsigned short* __restrict__ n1,      // ws: 5 MB bf16
    float*          __restrict__ n0,      // ws: 1 MB fp32
    float*          __restrict__ out)
{
    cg::grid_group grid = cg::this_grid();
    __shared__ __align__(16) unsigned short shA[2][16][LSTRIDE];   // 16.9 KB

    const int tid  = threadIdx.x;
    const int bid  = blockIdx.x;
    const int wv   = __builtin_amdgcn_readfirstlane(tid >> 6);     // 0..3
    const int lane = tid & 63;
    const int m    = lane & 15;        // MFMA row/col-in-tile
    const int q    = lane >> 4;        // quad

    // ---- phase 0: W0 -> bf16 B-fragments (blocks 0..31, one 64-lane unit per wave).
    if (bid < 32) {
        const int f128 = bid * 4 + wv;   // 0..127
        const int mat  = f128 >> 6;
        const int f    = f128 & 63;      // t*8 + kk
        const int t    = f >> 3, kk = f & 7;
        const float* W = mat ? W0n : W0s;
        __align__(16) unsigned short tmp[8];
        #pragma unroll
        for (int j = 0; j < 8; ++j)
            tmp[j] = f2bf(W[(kk * 32 + q * 8 + j) * HALF + t * 16 + m]);
        *(uint4*)(bfrag + ((size_t)(mat * 64 + f) * 64 + lane) * 8) = *(const uint4*)tmp;
    }
    __threadfence();
    grid.sync();

    // ---- phase A: fused gather + MFMA layer-0. Exactly one 16-row unit per block.
    {
        const bool hop1    = (bid < M1 / 16);
        const int  rowbase = hop1 ? bid * 16 : (bid - M1 / 16) * 16;
        if (hop1) gather4<F1>(feat, sn1, sn2, rowbase, wv, lane, shA);
        else      gather4<F0>(feat, sn0, sn1, rowbase, wv, lane, shA);
        __syncthreads();

        // 8 (h, t0-pair) tasks over 4 waves: wave wv does c = wv*2+p, p<2.
        #pragma unroll
        for (int p = 0; p < 2; ++p) {
            const int c  = wv * 2 + p;
            const int h  = c >> 2;           // 0: self/W0s, 1: agg/W0n
            const int t0 = (c & 3) * 2;      // tiles t0, t0+1 in half h

            f32x4 acc0 = {0.f, 0.f, 0.f, 0.f};
            f32x4 acc1 = {0.f, 0.f, 0.f, 0.f};
            #pragma unroll
            for (int kk = 0; kk < 8; ++kk) {
                const bf16x8 af = *(const bf16x8*)(&shA[h][m][kk * 32 + q * 8]);
                const bf16x8 b0 = *(const bf16x8*)(bfrag + ((size_t)(h * 64 + (t0 + 0) * 8 + kk) * 64 + lane) * 8);
                const bf16x8 b1 = *(const bf16x8*)(bfrag + ((size_t)(h * 64 + (t0 + 1) * 8 + kk) * 64 + lane) * 8);
                acc0 = __builtin_amdgcn_mfma_f32_16x16x32_bf16(af, b0, acc0, 0, 0, 0);
                acc1 = __builtin_amdgcn_mfma_f32_16x16x32_bf16(af, b1, acc1, 0, 0, 0);
            }
            // C/D layout: col = m, row = q*4 + reg  [verified R4-R7]
            #pragma unroll
            for (int reg = 0; reg < 4; ++reg) {
                const int row  = rowbase + q * 4 + reg;
                const int col0 = h * HALF + (t0 + 0) * 16 + m;
                const int col1 = h * HALF + (t0 + 1) * 16 + m;
                const float v0 = fmaxf(acc0[reg], 0.f);
                const float v1 = fmaxf(acc1[reg], 0.f);
                if (hop1) {
                    n1[(size_t)row * DIM + col0] = f2bf(v0);
                    n1[(size_t)row * DIM + col1] = f2bf(v1);
                } else {
                    n0[(size_t)row * DIM + col0] = v0;
                    n0[(size_t)row * DIM + col1] = v1;
                }
            }
        }
    }
    __threadfence();
    grid.sync();

    // ---- phase B: out[r] = concat(n0[r] @ W1s, mean10(n1[r*10..]) @ W1n). No act.
    float* sf = (float*)shA;   // [0:256) n0 row, [256:512) agg row
    const unsigned* n1u = (const unsigned*)n1;   // 128 uints per n1 row

    for (int r = bid; r < B0; r += GRID) {
        sf[tid] = n0[(size_t)r * DIM + tid];
        if (tid < 128) {
            float a0 = 0.f, a1 = 0.f;
            #pragma unroll
            for (int j = 0; j < F0; ++j) {
                const unsigned p = n1u[(size_t)(r * F0 + j) * 128 + tid];
                a0 += bf2f(p & 0xffffu);
                a1 += bf2f(p >> 16);
            }
            sf[256 + 2 * tid]     = a0 * (1.0f / F0);
            sf[256 + 2 * tid + 1] = a1 * (1.0f / F0);
        }
        __syncthreads();

        const bool nh  = (tid >= HALF);                     // wave-uniform
        const float* __restrict__ x = nh ? (sf + 256) : sf;
        const float* __restrict__ W = nh ? W1n : W1s;
        const int col = nh ? (tid - HALF) : tid;

        float acc = 0.f;
        #pragma unroll 8
        for (int d = 0; d < DIM; ++d)
            acc += x[d] * W[d * HALF + col];

        out[(size_t)r * DIM + tid] = acc;
        __syncthreads();   // protect sf before next r
    }
}

extern "C" void kernel_launch(void* const* d_in, const int* in_sizes, int n_in,
                              void* d_out, int out_size, void* d_ws, size_t ws_size,
                              hipStream_t stream) {
    (void)in_sizes; (void)n_in; (void)out_size; (void)ws_size;
    const float* feat = (const float*)d_in[0];
    const int*   sn0  = (const int*)  d_in[1];
    const int*   sn1  = (const int*)  d_in[2];
    const int*   sn2  = (const int*)  d_in[3];
    const float* W0s  = (const float*)d_in[4];
    const float* W0n  = (const float*)d_in[5];
    const float* W1s  = (const float*)d_in[6];
    const float* W1n  = (const float*)d_in[7];
    float* out = (float*)d_out;

    // ws layout (16B-aligned):
    //   [0, 5 MB)      n1 bf16     10240*256*2 = 5,242,880
    //   [+, 1 MB)      n0 fp32     1024*256*4  = 1,048,576
    //   [+, 128 KB)    W0 B-frags  131,072
    unsigned short* n1    = (unsigned short*)d_ws;
    float*          n0    = (float*)((char*)d_ws + 5242880);
    unsigned short* bfrag = (unsigned short*)((char*)d_ws + 5242880 + 1048576);

    void* args[] = { &feat, &sn0, &sn1, &sn2, &W0s, &W0n, &W1s, &W1n,
                     &bfrag, &n1, &n0, &out };
    hipLaunchCooperativeKernel((void*)sage_coop, dim3(GRID), dim3(256),
                               args, 0, stream);
}